// Round 1
// baseline (1091.049 us; speedup 1.0000x reference)
//
#include <hip/hip_runtime.h>

#define BM 64
#define BN 64
#define BK 16

#define MAX_ITER_N 20
#define F_TOL_F 1e-6f
#define FREE_NUM_N 64

#define BSZ 1024
#define IN_DIM 512
#define HID 1024
#define OUT_DIM 256
#define M_CON 128

// workspace layout (float offsets)
#define WS_BP    0
#define WS_H1    256
#define WS_H2    (WS_H1 + BSZ*HID)
#define WS_ZA    (WS_H2 + BSZ*HID)
#define WS_ZB    (WS_ZA + BSZ*OUT_DIM)
#define WS_RES   (WS_ZB + BSZ*OUT_DIM)
#define WS_CTRL  (WS_RES + 32)
// ctrl ints: [0]=stop, [1]=iter, [2]=cur

__global__ void init_k(unsigned int* __restrict__ res, int* __restrict__ ctrl) {
    int t = threadIdx.x;
    if (t < 32) res[t] = 0u;
    if (t == 0) { ctrl[0] = 0; ctrl[1] = 1; ctrl[2] = 0; }
}

__global__ void bias_proj_k(const float* __restrict__ b_vec,
                            const float* __restrict__ WbProj,
                            float* __restrict__ bp) {
    int j = threadIdx.x;  // 256 threads, 1 block
    float s = 0.0f;
    for (int k = 0; k < M_CON; ++k) s += b_vec[k] * WbProj[j * M_CON + k];
    bp[j] = s;
}

// C[M,N] = act(X[M,K] @ W[N,K]^T + bias[N]); optional second destination C2
template<bool RELU>
__global__ __launch_bounds__(256) void gemm_bias(
    const float* __restrict__ X, const float* __restrict__ W,
    const float* __restrict__ bias, float* __restrict__ C,
    float* __restrict__ C2, int M, int N, int K)
{
    __shared__ float Xs[BM][BK + 1];
    __shared__ float Ws[BN][BK + 1];
    const int tid = threadIdx.x;
    const int tx = tid & 15;
    const int ty = tid >> 4;
    const int row0 = blockIdx.y * BM;
    const int col0 = blockIdx.x * BN;
    const int lr = tid >> 2;
    const int lc = (tid & 3) << 2;

    float acc[4][4] = {};

    for (int k0 = 0; k0 < K; k0 += BK) {
        float4 xv = *(const float4*)(X + (row0 + lr) * K + k0 + lc);
        float4 wv = *(const float4*)(W + (col0 + lr) * K + k0 + lc);
        Xs[lr][lc + 0] = xv.x; Xs[lr][lc + 1] = xv.y;
        Xs[lr][lc + 2] = xv.z; Xs[lr][lc + 3] = xv.w;
        Ws[lr][lc + 0] = wv.x; Ws[lr][lc + 1] = wv.y;
        Ws[lr][lc + 2] = wv.z; Ws[lr][lc + 3] = wv.w;
        __syncthreads();
#pragma unroll
        for (int kk = 0; kk < BK; ++kk) {
            float a[4], b[4];
#pragma unroll
            for (int r = 0; r < 4; ++r) a[r] = Xs[4 * ty + r][kk];
#pragma unroll
            for (int c = 0; c < 4; ++c) b[c] = Ws[4 * tx + c][kk];
#pragma unroll
            for (int r = 0; r < 4; ++r)
#pragma unroll
                for (int c = 0; c < 4; ++c)
                    acc[r][c] += a[r] * b[c];
        }
        __syncthreads();
    }

    const int gj0 = col0 + 4 * tx;
    float4 bb = *(const float4*)(bias + gj0);
    float bv[4] = {bb.x, bb.y, bb.z, bb.w};
#pragma unroll
    for (int r = 0; r < 4; ++r) {
        int gi = row0 + 4 * ty + r;
        float4 v;
        float* vp = (float*)&v;
#pragma unroll
        for (int c = 0; c < 4; ++c) {
            float t = acc[r][c] + bv[c];
            if (RELU) t = fmaxf(t, 0.0f);
            vp[c] = t;
        }
        *(float4*)(C + gi * N + gj0) = v;
        if (C2) *(float4*)(C2 + gi * N + gj0) = v;
    }
}

// z_new = bias_proj + z @ WzProj^T, relu on cols >= FREE_NUM; ping-pong via ctrl[2]
__global__ __launch_bounds__(256) void z_update_k(
    float* __restrict__ zA, float* __restrict__ zB,
    const float* __restrict__ Wz, const float* __restrict__ bp,
    const int* __restrict__ ctrl)
{
    if (ctrl[0]) return;
    const int cur = ctrl[2];
    const float* zin = cur ? zB : zA;
    float* zout = cur ? zA : zB;

    __shared__ float Xs[BM][BK + 1];
    __shared__ float Ws[BN][BK + 1];
    const int tid = threadIdx.x;
    const int tx = tid & 15;
    const int ty = tid >> 4;
    const int row0 = blockIdx.y * BM;
    const int col0 = blockIdx.x * BN;
    const int lr = tid >> 2;
    const int lc = (tid & 3) << 2;
    const int K = OUT_DIM, N = OUT_DIM;

    float acc[4][4] = {};

    for (int k0 = 0; k0 < K; k0 += BK) {
        float4 xv = *(const float4*)(zin + (row0 + lr) * K + k0 + lc);
        float4 wv = *(const float4*)(Wz + (col0 + lr) * K + k0 + lc);
        Xs[lr][lc + 0] = xv.x; Xs[lr][lc + 1] = xv.y;
        Xs[lr][lc + 2] = xv.z; Xs[lr][lc + 3] = xv.w;
        Ws[lr][lc + 0] = wv.x; Ws[lr][lc + 1] = wv.y;
        Ws[lr][lc + 2] = wv.z; Ws[lr][lc + 3] = wv.w;
        __syncthreads();
#pragma unroll
        for (int kk = 0; kk < BK; ++kk) {
            float a[4], b[4];
#pragma unroll
            for (int r = 0; r < 4; ++r) a[r] = Xs[4 * ty + r][kk];
#pragma unroll
            for (int c = 0; c < 4; ++c) b[c] = Ws[4 * tx + c][kk];
#pragma unroll
            for (int r = 0; r < 4; ++r)
#pragma unroll
                for (int c = 0; c < 4; ++c)
                    acc[r][c] += a[r] * b[c];
        }
        __syncthreads();
    }

    const int gj0 = col0 + 4 * tx;
    float4 bb = *(const float4*)(bp + gj0);
    float bv[4] = {bb.x, bb.y, bb.z, bb.w};
#pragma unroll
    for (int r = 0; r < 4; ++r) {
        int gi = row0 + 4 * ty + r;
        float4 v;
        float* vp = (float*)&v;
#pragma unroll
        for (int c = 0; c < 4; ++c) {
            int gj = gj0 + c;
            float t = acc[r][c] + bv[c];
            if (gj >= FREE_NUM_N) t = fmaxf(t, 0.0f);
            vp[c] = t;
        }
        *(float4*)(zout + gi * N + gj0) = v;
    }
}

// res = max |z_new @ A^T - b_vec|, atomicMax into res slot (uint bits, values >= 0)
__global__ __launch_bounds__(256) void residual_k(
    const float* __restrict__ zA, const float* __restrict__ zB,
    const float* __restrict__ Amat, const float* __restrict__ bvec,
    const int* __restrict__ ctrl, unsigned int* __restrict__ res)
{
    if (ctrl[0]) return;
    const float* z = ctrl[2] ? zA : zB;   // z_new lives in buffer (cur ^ 1)

    __shared__ float Xs[BM][BK + 1];
    __shared__ float Ws[BN][BK + 1];
    __shared__ float red[256];
    const int tid = threadIdx.x;
    const int tx = tid & 15;
    const int ty = tid >> 4;
    const int row0 = blockIdx.y * BM;
    const int col0 = blockIdx.x * BN;
    const int lr = tid >> 2;
    const int lc = (tid & 3) << 2;
    const int K = OUT_DIM;

    float acc[4][4] = {};

    for (int k0 = 0; k0 < K; k0 += BK) {
        float4 xv = *(const float4*)(z + (row0 + lr) * K + k0 + lc);
        float4 wv = *(const float4*)(Amat + (col0 + lr) * K + k0 + lc);
        Xs[lr][lc + 0] = xv.x; Xs[lr][lc + 1] = xv.y;
        Xs[lr][lc + 2] = xv.z; Xs[lr][lc + 3] = xv.w;
        Ws[lr][lc + 0] = wv.x; Ws[lr][lc + 1] = wv.y;
        Ws[lr][lc + 2] = wv.z; Ws[lr][lc + 3] = wv.w;
        __syncthreads();
#pragma unroll
        for (int kk = 0; kk < BK; ++kk) {
            float a[4], b[4];
#pragma unroll
            for (int r = 0; r < 4; ++r) a[r] = Xs[4 * ty + r][kk];
#pragma unroll
            for (int c = 0; c < 4; ++c) b[c] = Ws[4 * tx + c][kk];
#pragma unroll
            for (int r = 0; r < 4; ++r)
#pragma unroll
                for (int c = 0; c < 4; ++c)
                    acc[r][c] += a[r] * b[c];
        }
        __syncthreads();
    }

    const int gj0 = col0 + 4 * tx;
    float4 bb = *(const float4*)(bvec + gj0);
    float bv[4] = {bb.x, bb.y, bb.z, bb.w};
    float lmax = 0.0f;
#pragma unroll
    for (int r = 0; r < 4; ++r)
#pragma unroll
        for (int c = 0; c < 4; ++c)
            lmax = fmaxf(lmax, fabsf(acc[r][c] - bv[c]));

    red[tid] = lmax;
    __syncthreads();
    for (int s = 128; s > 0; s >>= 1) {
        if (tid < s) red[tid] = fmaxf(red[tid], red[tid + s]);
        __syncthreads();
    }
    if (tid == 0) atomicMax(res, __float_as_uint(red[0]));
}

__global__ void finalize_k(int* __restrict__ ctrl, const unsigned int* __restrict__ res) {
    if (ctrl[0]) return;
    ctrl[1] += 1;   // body executed: it += 1
    ctrl[2] ^= 1;   // flip current z buffer
    float r = __uint_as_float(*res);
    if (!(r > F_TOL_F)) ctrl[0] = 1;  // stop (covers res<=tol and NaN)
}

__global__ void final_write_k(const float* __restrict__ zA, const float* __restrict__ zB,
                              const int* __restrict__ ctrl, float* __restrict__ out) {
    int idx = blockIdx.x * blockDim.x + threadIdx.x;
    const float* z = ctrl[2] ? zB : zA;
    out[idx] = z[idx];
    if (idx == 0) out[2 * BSZ * OUT_DIM] = (float)ctrl[1];
}

extern "C" void kernel_launch(void* const* d_in, const int* in_sizes, int n_in,
                              void* d_out, int out_size, void* d_ws, size_t ws_size,
                              hipStream_t stream) {
    const float* b_primal = (const float*)d_in[0];
    const float* W0     = (const float*)d_in[1];
    const float* b0     = (const float*)d_in[2];
    const float* W1     = (const float*)d_in[3];
    const float* b1     = (const float*)d_in[4];
    const float* W2     = (const float*)d_in[5];
    const float* b2     = (const float*)d_in[6];
    const float* Amat   = (const float*)d_in[7];
    const float* b_vec  = (const float*)d_in[8];
    const float* WzProj = (const float*)d_in[9];
    const float* WbProj = (const float*)d_in[10];
    float* out = (float*)d_out;
    float* ws  = (float*)d_ws;

    float* bp = ws + WS_BP;
    float* h1 = ws + WS_H1;
    float* h2 = ws + WS_H2;
    float* zA = ws + WS_ZA;
    float* zB = ws + WS_ZB;
    unsigned int* res = (unsigned int*)(ws + WS_RES);
    int* ctrl = (int*)(ws + WS_CTRL);

    hipLaunchKernelGGL(init_k, dim3(1), dim3(64), 0, stream, res, ctrl);
    hipLaunchKernelGGL(bias_proj_k, dim3(1), dim3(256), 0, stream, b_vec, WbProj, bp);

    // h1 = relu(X @ W0^T + b0)
    hipLaunchKernelGGL((gemm_bias<true>), dim3(HID / BN, BSZ / BM), dim3(256), 0, stream,
                       b_primal, W0, b0, h1, (float*)nullptr, BSZ, HID, IN_DIM);
    // h2 = relu(h1 @ W1^T + b1)
    hipLaunchKernelGGL((gemm_bias<true>), dim3(HID / BN, BSZ / BM), dim3(256), 0, stream,
                       h1, W1, b1, h2, (float*)nullptr, BSZ, HID, HID);
    // out = h2 @ W2^T + b2  -> d_out chunk 1 AND zA (loop init)
    hipLaunchKernelGGL((gemm_bias<false>), dim3(OUT_DIM / BN, BSZ / BM), dim3(256), 0, stream,
                       h2, W2, b2, out + BSZ * OUT_DIM, zA, BSZ, OUT_DIM, HID);

    for (int t = 0; t < MAX_ITER_N; ++t) {
        hipLaunchKernelGGL(z_update_k, dim3(OUT_DIM / BN, BSZ / BM), dim3(256), 0, stream,
                           zA, zB, WzProj, bp, ctrl);
        hipLaunchKernelGGL(residual_k, dim3(M_CON / BN, BSZ / BM), dim3(256), 0, stream,
                           zA, zB, Amat, b_vec, ctrl, res + t);
        hipLaunchKernelGGL(finalize_k, dim3(1), dim3(1), 0, stream, ctrl, res + t);
    }

    hipLaunchKernelGGL(final_write_k, dim3(BSZ * OUT_DIM / 256), dim3(256), 0, stream,
                       zA, zB, ctrl, out);
}

// Round 2
// 306.010 us; speedup vs baseline: 3.5654x; 3.5654x over previous
//
#include <hip/hip_runtime.h>

typedef __attribute__((ext_vector_type(8))) __bf16 bf16x8;
typedef __attribute__((ext_vector_type(4))) float f32x4;

#define BM 64
#define BN 64
#define BK 16

#define MAX_ITER_N 20
#define F_TOL_F 1e-6f
#define FREE_NUM_N 64

#define BSZ 1024
#define IN_DIM 512
#define HID 1024
#define OUT_DIM 256
#define M_CON 128

// workspace layout (float offsets)
#define WS_BP    0
#define WS_H1    256
#define WS_H2    (WS_H1 + BSZ*HID)
#define WS_ZA    (WS_H2 + BSZ*HID)
#define WS_RES   (WS_ZA + BSZ*OUT_DIM)
#define WS_CTRL  (WS_RES + 32)
#define WS_WZG   (WS_CTRL + 8)                 // bf16 Wz: 65536 ushort = 32768 floats
#define WS_AG    (WS_WZG + 32768)              // bf16 A: 32768 ushort = 16384 floats

__device__ inline unsigned short f2bf(float f) {
    unsigned int u = __float_as_uint(f);
    u += 0x7fffu + ((u >> 16) & 1u);
    return (unsigned short)(u >> 16);
}

__global__ void init_k(unsigned int* __restrict__ res) {
    int t = threadIdx.x;
    if (t < 32) res[t] = 0u;
}

__global__ void bias_proj_k(const float* __restrict__ b_vec,
                            const float* __restrict__ WbProj,
                            float* __restrict__ bp) {
    int j = threadIdx.x;  // 256 threads, 1 block
    float s = 0.0f;
    for (int k = 0; k < M_CON; ++k) s += b_vec[k] * WbProj[j * M_CON + k];
    bp[j] = s;
}

__global__ void convert_k(const float* __restrict__ Wz, const float* __restrict__ A,
                          unsigned short* __restrict__ WzG, unsigned short* __restrict__ AG) {
    int i = blockIdx.x * 256 + threadIdx.x;
    if (i < OUT_DIM * OUT_DIM) WzG[i] = f2bf(Wz[i]);
    else AG[i - OUT_DIM * OUT_DIM] = f2bf(A[i - OUT_DIM * OUT_DIM]);
}

// C[M,N] = act(X[M,K] @ W[N,K]^T + bias[N])  (fp32, round-1 kernel, unchanged)
template<bool RELU>
__global__ __launch_bounds__(256) void gemm_bias(
    const float* __restrict__ X, const float* __restrict__ W,
    const float* __restrict__ bias, float* __restrict__ C,
    int M, int N, int K)
{
    __shared__ float Xs[BM][BK + 1];
    __shared__ float Ws[BN][BK + 1];
    const int tid = threadIdx.x;
    const int tx = tid & 15;
    const int ty = tid >> 4;
    const int row0 = blockIdx.y * BM;
    const int col0 = blockIdx.x * BN;
    const int lr = tid >> 2;
    const int lc = (tid & 3) << 2;

    float acc[4][4] = {};

    for (int k0 = 0; k0 < K; k0 += BK) {
        float4 xv = *(const float4*)(X + (row0 + lr) * K + k0 + lc);
        float4 wv = *(const float4*)(W + (col0 + lr) * K + k0 + lc);
        Xs[lr][lc + 0] = xv.x; Xs[lr][lc + 1] = xv.y;
        Xs[lr][lc + 2] = xv.z; Xs[lr][lc + 3] = xv.w;
        Ws[lr][lc + 0] = wv.x; Ws[lr][lc + 1] = wv.y;
        Ws[lr][lc + 2] = wv.z; Ws[lr][lc + 3] = wv.w;
        __syncthreads();
#pragma unroll
        for (int kk = 0; kk < BK; ++kk) {
            float a[4], b[4];
#pragma unroll
            for (int r = 0; r < 4; ++r) a[r] = Xs[4 * ty + r][kk];
#pragma unroll
            for (int c = 0; c < 4; ++c) b[c] = Ws[4 * tx + c][kk];
#pragma unroll
            for (int r = 0; r < 4; ++r)
#pragma unroll
                for (int c = 0; c < 4; ++c)
                    acc[r][c] += a[r] * b[c];
        }
        __syncthreads();
    }

    const int gj0 = col0 + 4 * tx;
    float4 bb = *(const float4*)(bias + gj0);
    float bv[4] = {bb.x, bb.y, bb.z, bb.w};
#pragma unroll
    for (int r = 0; r < 4; ++r) {
        int gi = row0 + 4 * ty + r;
        float4 v;
        float* vp = (float*)&v;
#pragma unroll
        for (int c = 0; c < 4; ++c) {
            float t = acc[r][c] + bv[c];
            if (RELU) t = fmaxf(t, 0.0f);
            vp[c] = t;
        }
        *(float4*)(C + gi * N + gj0) = v;
    }
}

// Fused 20-iteration fixed-point loop. 64 blocks x 256 threads; block owns 16 rows.
// z lives in LDS (bf16); Wz/A read as bf16 from global (L2-resident); MFMA 16x16x32.
__global__ __launch_bounds__(256) void loop_fused_k(
    const float* __restrict__ z0,             // MLP out [1024][256] f32
    const unsigned short* __restrict__ WzG,   // bf16 [256][256]
    const unsigned short* __restrict__ AG,    // bf16 [128][256]
    const float* __restrict__ bp,
    const float* __restrict__ b_vec,
    float* __restrict__ zA,                   // f32 z_20 out
    unsigned int* __restrict__ res)           // res[t-1] = residual of iteration t
{
    __shared__ unsigned short zS[16][264];    // 16 rows x 256 cols, pad 8 bf16
    __shared__ float red[4];

    const int tid  = threadIdx.x;
    const int wave = tid >> 6;
    const int lane = tid & 63;
    const int ln   = lane & 15;
    const int q    = lane >> 4;
    const int r0   = blockIdx.x * 16;

    // fill zS = bf16(z0 rows)
    {
        int row = tid >> 4;
        int c0  = (tid & 15) * 16;
        const float* src = z0 + (r0 + row) * OUT_DIM + c0;
#pragma unroll
        for (int i = 0; i < 16; ++i) zS[row][c0 + i] = f2bf(src[i]);
    }

    // preload residual B-frags (A matrix), b_vec, bias_proj, columns
    bf16x8 afr[2][8];
    float bvv[2];
#pragma unroll
    for (int mt = 0; mt < 2; ++mt) {
        int m = wave * 32 + mt * 16 + ln;
        bvv[mt] = b_vec[m];
#pragma unroll
        for (int ks = 0; ks < 8; ++ks)
            afr[mt][ks] = __builtin_bit_cast(bf16x8, *(const uint4*)(AG + m * OUT_DIM + ks * 32 + q * 8));
    }
    int colg[4];
    float bpv[4];
#pragma unroll
    for (int nt = 0; nt < 4; ++nt) {
        colg[nt] = wave * 64 + nt * 16 + ln;
        bpv[nt]  = bp[colg[nt]];
    }

    __syncthreads();

    // z A-frags: zS[m=ln][k = ks*32 + q*8 .. +7]
    bf16x8 zfr[8];
#pragma unroll
    for (int ks = 0; ks < 8; ++ks)
        zfr[ks] = __builtin_bit_cast(bf16x8, *(const uint4*)&zS[ln][ks * 32 + q * 8]);

    const f32x4 zero4 = {0.f, 0.f, 0.f, 0.f};

    for (int t = 1; t <= MAX_ITER_N; ++t) {
        // z_new = bp + z @ Wz^T  (wave covers cols wave*64 .. wave*64+63)
        f32x4 acc[4];
#pragma unroll
        for (int nt = 0; nt < 4; ++nt) acc[nt] = zero4;
#pragma unroll
        for (int nt = 0; nt < 4; ++nt) {
            const unsigned short* wrow = WzG + colg[nt] * OUT_DIM + q * 8;
#pragma unroll
            for (int ks = 0; ks < 8; ++ks) {
                bf16x8 bfr = __builtin_bit_cast(bf16x8, *(const uint4*)(wrow + ks * 32));
                acc[nt] = __builtin_amdgcn_mfma_f32_16x16x32_bf16(zfr[ks], bfr, acc[nt], 0, 0, 0);
            }
        }
        float vals[4][4];
#pragma unroll
        for (int nt = 0; nt < 4; ++nt)
#pragma unroll
            for (int i = 0; i < 4; ++i) {
                float v = acc[nt][i] + bpv[nt];
                if (colg[nt] >= FREE_NUM_N) v = fmaxf(v, 0.0f);
                vals[nt][i] = v;
            }
        if (t == MAX_ITER_N) {  // write f32 z_20 (pre-rounding) to global
#pragma unroll
            for (int nt = 0; nt < 4; ++nt)
#pragma unroll
                for (int i = 0; i < 4; ++i)
                    zA[(r0 + q * 4 + i) * OUT_DIM + colg[nt]] = vals[nt][i];
        }
        __syncthreads();   // S1: all waves done reading zS (z_{t-1})
#pragma unroll
        for (int nt = 0; nt < 4; ++nt)
#pragma unroll
            for (int i = 0; i < 4; ++i)
                zS[q * 4 + i][colg[nt]] = f2bf(vals[nt][i]);
        __syncthreads();   // S2: zS = z_t complete
#pragma unroll
        for (int ks = 0; ks < 8; ++ks)
            zfr[ks] = __builtin_bit_cast(bf16x8, *(const uint4*)&zS[ln][ks * 32 + q * 8]);

        // residual: u = z_t @ A^T ; res = max |u - b_vec|
        f32x4 acc2[2];
        acc2[0] = zero4; acc2[1] = zero4;
#pragma unroll
        for (int mt = 0; mt < 2; ++mt)
#pragma unroll
            for (int ks = 0; ks < 8; ++ks)
                acc2[mt] = __builtin_amdgcn_mfma_f32_16x16x32_bf16(zfr[ks], afr[mt][ks], acc2[mt], 0, 0, 0);
        float lmax = 0.0f;
#pragma unroll
        for (int mt = 0; mt < 2; ++mt)
#pragma unroll
            for (int i = 0; i < 4; ++i)
                lmax = fmaxf(lmax, fabsf(acc2[mt][i] - bvv[mt]));
#pragma unroll
        for (int off = 32; off > 0; off >>= 1)
            lmax = fmaxf(lmax, __shfl_xor(lmax, off));
        if (lane == 0) red[wave] = lmax;
        __syncthreads();   // S3: red ready; frag loads complete
        if (tid == 0) {
            float bm = fmaxf(fmaxf(red[0], red[1]), fmaxf(red[2], red[3]));
            atomicMax(res + (t - 1), __float_as_uint(bm));
        }
    }
}

// Replays the reference's while-loop stopping rule exactly.
__global__ void decide_k(const unsigned int* __restrict__ res, int* __restrict__ ctrl,
                         float* __restrict__ out) {
    int T = MAX_ITER_N;
    for (int t = 0; t < MAX_ITER_N; ++t) {
        float r = __uint_as_float(res[t]);
        if (!(r > F_TOL_F)) { T = t + 1; break; }  // covers res<=tol and NaN
    }
    ctrl[0] = T;
    out[2 * BSZ * OUT_DIM] = (float)(T + 1);  // curr_iter
}

// Cold path: if early stop fired at T<20, recompute T iterations in fp32.
__global__ __launch_bounds__(256) void fallback_k(
    const float* __restrict__ z0, const float* __restrict__ Wz,
    const float* __restrict__ bp, const int* __restrict__ ctrl,
    float* __restrict__ zA)
{
    const int T = ctrl[0];
    if (T >= MAX_ITER_N) return;
    __shared__ float zS[16][257];
    const int r0 = blockIdx.x * 16;
    const int tid = threadIdx.x;
    const int row = tid >> 4;
    const int c0 = (tid & 15) * 16;
    for (int i = 0; i < 16; ++i) zS[row][c0 + i] = z0[(r0 + row) * OUT_DIM + c0 + i];
    __syncthreads();
    const int j = tid;
    const float bj = bp[j];
    for (int t = 0; t < T; ++t) {
        float acc[16] = {};
        for (int k = 0; k < OUT_DIM; ++k) {
            float w = Wz[j * OUT_DIM + k];
#pragma unroll
            for (int r = 0; r < 16; ++r) acc[r] += zS[r][k] * w;
        }
        __syncthreads();
#pragma unroll
        for (int r = 0; r < 16; ++r) {
            float v = acc[r] + bj;
            if (j >= FREE_NUM_N) v = fmaxf(v, 0.0f);
            zS[r][j] = v;
        }
        __syncthreads();
    }
    for (int i = 0; i < 16; ++i) zA[(r0 + row) * OUT_DIM + c0 + i] = zS[row][c0 + i];
}

__global__ void final_copy_k(const float* __restrict__ zA, float* __restrict__ out) {
    int idx = blockIdx.x * blockDim.x + threadIdx.x;
    out[idx] = zA[idx];
}

extern "C" void kernel_launch(void* const* d_in, const int* in_sizes, int n_in,
                              void* d_out, int out_size, void* d_ws, size_t ws_size,
                              hipStream_t stream) {
    const float* b_primal = (const float*)d_in[0];
    const float* W0     = (const float*)d_in[1];
    const float* b0     = (const float*)d_in[2];
    const float* W1     = (const float*)d_in[3];
    const float* b1     = (const float*)d_in[4];
    const float* W2     = (const float*)d_in[5];
    const float* b2     = (const float*)d_in[6];
    const float* Amat   = (const float*)d_in[7];
    const float* b_vec  = (const float*)d_in[8];
    const float* WzProj = (const float*)d_in[9];
    const float* WbProj = (const float*)d_in[10];
    float* out = (float*)d_out;
    float* ws  = (float*)d_ws;

    float* bp = ws + WS_BP;
    float* h1 = ws + WS_H1;
    float* h2 = ws + WS_H2;
    float* zA = ws + WS_ZA;
    unsigned int* res = (unsigned int*)(ws + WS_RES);
    int* ctrl = (int*)(ws + WS_CTRL);
    unsigned short* WzG = (unsigned short*)(ws + WS_WZG);
    unsigned short* AG  = (unsigned short*)(ws + WS_AG);

    float* outz = out + BSZ * OUT_DIM;  // MLP output chunk (also z_0)

    hipLaunchKernelGGL(init_k, dim3(1), dim3(64), 0, stream, res);
    hipLaunchKernelGGL(bias_proj_k, dim3(1), dim3(256), 0, stream, b_vec, WbProj, bp);
    hipLaunchKernelGGL(convert_k, dim3((OUT_DIM * OUT_DIM + M_CON * OUT_DIM) / 256), dim3(256),
                       0, stream, WzProj, Amat, WzG, AG);

    hipLaunchKernelGGL((gemm_bias<true>), dim3(HID / BN, BSZ / BM), dim3(256), 0, stream,
                       b_primal, W0, b0, h1, BSZ, HID, IN_DIM);
    hipLaunchKernelGGL((gemm_bias<true>), dim3(HID / BN, BSZ / BM), dim3(256), 0, stream,
                       h1, W1, b1, h2, BSZ, HID, HID);
    hipLaunchKernelGGL((gemm_bias<false>), dim3(OUT_DIM / BN, BSZ / BM), dim3(256), 0, stream,
                       h2, W2, b2, outz, BSZ, OUT_DIM, HID);

    hipLaunchKernelGGL(loop_fused_k, dim3(BSZ / 16), dim3(256), 0, stream,
                       outz, WzG, AG, bp, b_vec, zA, res);
    hipLaunchKernelGGL(decide_k, dim3(1), dim3(1), 0, stream, res, ctrl, out);
    hipLaunchKernelGGL(fallback_k, dim3(BSZ / 16), dim3(256), 0, stream,
                       outz, WzProj, bp, ctrl, zA);
    hipLaunchKernelGGL(final_copy_k, dim3(BSZ * OUT_DIM / 256), dim3(256), 0, stream,
                       zA, out);
}

// Round 3
// 148.087 us; speedup vs baseline: 7.3676x; 2.0664x over previous
//
#include <hip/hip_runtime.h>

typedef __attribute__((ext_vector_type(8))) __bf16 bf16x8;
typedef __attribute__((ext_vector_type(4))) float f32x4;

#define MAX_ITER_N 20
#define F_TOL_F 1e-6f
#define FREE_NUM_N 64

#define BSZ 1024
#define IN_DIM 512
#define HID 1024
#define OUT_DIM 256
#define M_CON 128

// workspace layout (float offsets); all region starts multiple of 8 floats (32B)
#define WS_BP    0
#define WS_RES   256
#define WS_CTRL  288
#define WS_H1    296                       // 1024x1024 ushort = 524288 floats
#define WS_H2    (WS_H1 + 524288)
#define WS_APC   (WS_H2 + 524288)          // 1024x512 ushort
#define WS_W0C   (WS_APC + 262144)
#define WS_W1C   (WS_W0C + 262144)         // 1024x1024 ushort
#define WS_W2C   (WS_W1C + 524288)         // 256x1024 ushort
#define WS_WZG   (WS_W2C + 131072)         // 256x256 ushort
#define WS_AG    (WS_WZG + 32768)          // 128x256 ushort

__device__ __forceinline__ unsigned short f2bf(float f) {
    unsigned int u = __float_as_uint(f);
    u += 0x7fffu + ((u >> 16) & 1u);
    return (unsigned short)(u >> 16);
}

__device__ __forceinline__ void gload_lds16(const unsigned short* g, unsigned short* l) {
    __builtin_amdgcn_global_load_lds(
        (const __attribute__((address_space(1))) unsigned int*)(const void*)g,
        (__attribute__((address_space(3))) unsigned int*)(void*)l, 16, 0, 0);
}

// ---- prep: convert everything to bf16 + bias_proj + res init, one launch ----
// blocks [0,2400): conversion, 1024 elems/block; block 2400: bias_proj + res init
__global__ __launch_bounds__(256) void prep_k(
    const float* __restrict__ b_primal, const float* __restrict__ W0,
    const float* __restrict__ W1, const float* __restrict__ W2,
    const float* __restrict__ Wz, const float* __restrict__ Am,
    const float* __restrict__ b_vec, const float* __restrict__ WbProj,
    unsigned short* __restrict__ APc, unsigned short* __restrict__ W0c,
    unsigned short* __restrict__ W1c, unsigned short* __restrict__ W2c,
    unsigned short* __restrict__ WzG, unsigned short* __restrict__ AG,
    float* __restrict__ bp, unsigned int* __restrict__ res)
{
    int b = blockIdx.x;
    if (b >= 2400) {
        int j = threadIdx.x;
        float s = 0.0f;
        for (int k = 0; k < M_CON; ++k) s += b_vec[k] * WbProj[j * M_CON + k];
        bp[j] = s;
        if (j < 32) res[j] = 0u;
        return;
    }
    const float* src; unsigned short* dst; int off;
    if (b < 512)       { src = b_primal; dst = APc; off = b; }
    else if (b < 1024) { src = W0; dst = W0c; off = b - 512; }
    else if (b < 2048) { src = W1; dst = W1c; off = b - 1024; }
    else if (b < 2304) { src = W2; dst = W2c; off = b - 2048; }
    else if (b < 2368) { src = Wz; dst = WzG; off = b - 2304; }
    else               { src = Am; dst = AG;  off = b - 2368; }
    int idx = off * 1024 + threadIdx.x * 4;
    float4 v = *(const float4*)(src + idx);
    ushort4 o;
    o.x = f2bf(v.x); o.y = f2bf(v.y); o.z = f2bf(v.z); o.w = f2bf(v.w);
    *(ushort4*)(dst + idx) = o;
}

// ---- bf16 MFMA GEMM: C[M,N] = act(A[M,K] @ B[N,K]^T + bias) ----
// 64x64 tile, BK=64, 256 thr (4 waves 2x2), global_load_lds staging with
// XOR-swizzled granules (global source permuted so LDS dest stays lane-linear).
__device__ __forceinline__ void stage_tile(const unsigned short* __restrict__ src,
                                           unsigned short* lds, int ldK, int w, int lane) {
#pragma unroll
    for (int i = 0; i < 2; ++i) {
        int gbase = i * 256 + w * 64;          // wave-uniform granule base
        int g = gbase + lane;                  // this lane's LDS granule
        int row = g >> 3;
        int sgc = (g & 7) ^ (row & 7);         // permuted global granule
        gload_lds16(src + row * ldK + sgc * 8, lds + gbase * 8);
    }
}

__device__ __forceinline__ bf16x8 frag_ld(const unsigned short* lds, int row, int j) {
    int phys = j ^ (row & 7);
    return __builtin_bit_cast(bf16x8, *(const uint4*)(lds + row * 64 + phys * 8));
}

template<int K, bool RELU, bool F32OUT>
__global__ __launch_bounds__(256) void mfma_gemm(
    const unsigned short* __restrict__ A,   // [M][K]
    const unsigned short* __restrict__ B,   // [N][K]
    const float* __restrict__ bias,         // [N]
    void* __restrict__ Cv, int N_)
{
    __shared__ __align__(16) unsigned short As[64 * 64];
    __shared__ __align__(16) unsigned short Bs[64 * 64];
    const int tid = threadIdx.x;
    const int w = tid >> 6;
    const int lane = tid & 63;
    const int ln = lane & 15;
    const int q  = lane >> 4;
    const int row0 = blockIdx.y * 64;
    const int col0 = blockIdx.x * 64;

    const unsigned short* Ab = A + row0 * K;
    const unsigned short* Bb = B + col0 * K;

    f32x4 acc[2][2];
#pragma unroll
    for (int rt = 0; rt < 2; ++rt)
#pragma unroll
        for (int ct = 0; ct < 2; ++ct)
            acc[rt][ct] = (f32x4){0.f, 0.f, 0.f, 0.f};

    for (int k0 = 0; k0 < K; k0 += 64) {
        stage_tile(Ab + k0, As, K, w, lane);
        stage_tile(Bb + k0, Bs, K, w, lane);
        __syncthreads();
#pragma unroll
        for (int ks = 0; ks < 2; ++ks) {
            bf16x8 af[2], bfv[2];
#pragma unroll
            for (int rt = 0; rt < 2; ++rt)
                af[rt] = frag_ld(As, (w >> 1) * 32 + rt * 16 + ln, ks * 4 + q);
#pragma unroll
            for (int ct = 0; ct < 2; ++ct)
                bfv[ct] = frag_ld(Bs, (w & 1) * 32 + ct * 16 + ln, ks * 4 + q);
#pragma unroll
            for (int rt = 0; rt < 2; ++rt)
#pragma unroll
                for (int ct = 0; ct < 2; ++ct)
                    acc[rt][ct] = __builtin_amdgcn_mfma_f32_16x16x32_bf16(
                        af[rt], bfv[ct], acc[rt][ct], 0, 0, 0);
        }
        __syncthreads();
    }

    float bv[2];
#pragma unroll
    for (int ct = 0; ct < 2; ++ct)
        bv[ct] = bias[col0 + (w & 1) * 32 + ct * 16 + ln];
#pragma unroll
    for (int rt = 0; rt < 2; ++rt)
#pragma unroll
        for (int ct = 0; ct < 2; ++ct) {
            int c = col0 + (w & 1) * 32 + ct * 16 + ln;
#pragma unroll
            for (int i = 0; i < 4; ++i) {
                int r = row0 + (w >> 1) * 32 + rt * 16 + q * 4 + i;
                float v = acc[rt][ct][i] + bv[ct];
                if (RELU) v = fmaxf(v, 0.0f);
                if (F32OUT) ((float*)Cv)[r * N_ + c] = v;
                else ((unsigned short*)Cv)[r * N_ + c] = f2bf(v);
            }
        }
}

// ---- fused 20-iteration fixed-point loop; Wz/A frags register-resident ----
__global__ __launch_bounds__(256, 1) void loop_fused_k(
    const float* __restrict__ z0,             // MLP out [1024][256] f32
    const unsigned short* __restrict__ WzG,   // bf16 [256][256]
    const unsigned short* __restrict__ AG,    // bf16 [128][256]
    const float* __restrict__ bp,
    const float* __restrict__ b_vec,
    float* __restrict__ zout_g,               // f32 z_20 out (d_out chunk 0)
    unsigned int* __restrict__ res)
{
    __shared__ unsigned short zS[16][264];
    __shared__ float red[4];

    const int tid  = threadIdx.x;
    const int wave = tid >> 6;
    const int lane = tid & 63;
    const int ln   = lane & 15;
    const int q    = lane >> 4;
    const int r0   = blockIdx.x * 16;

    {
        int row = tid >> 4;
        int c0  = (tid & 15) * 16;
        const float* src = z0 + (r0 + row) * OUT_DIM + c0;
#pragma unroll
        for (int i = 0; i < 16; ++i) zS[row][c0 + i] = f2bf(src[i]);
    }

    // register-resident operand fragments
    bf16x8 afr[2][8];
    float bvv[2];
#pragma unroll
    for (int mt = 0; mt < 2; ++mt) {
        int m = wave * 32 + mt * 16 + ln;
        bvv[mt] = b_vec[m];
#pragma unroll
        for (int ks = 0; ks < 8; ++ks)
            afr[mt][ks] = __builtin_bit_cast(bf16x8, *(const uint4*)(AG + m * OUT_DIM + ks * 32 + q * 8));
    }
    int colg[4];
    float bpv[4];
    bf16x8 wzfr[4][8];
#pragma unroll
    for (int nt = 0; nt < 4; ++nt) {
        colg[nt] = wave * 64 + nt * 16 + ln;
        bpv[nt]  = bp[colg[nt]];
#pragma unroll
        for (int ks = 0; ks < 8; ++ks)
            wzfr[nt][ks] = __builtin_bit_cast(bf16x8, *(const uint4*)(WzG + colg[nt] * OUT_DIM + ks * 32 + q * 8));
    }

    __syncthreads();

    bf16x8 zfr[8];
#pragma unroll
    for (int ks = 0; ks < 8; ++ks)
        zfr[ks] = __builtin_bit_cast(bf16x8, *(const uint4*)&zS[ln][ks * 32 + q * 8]);

    const f32x4 zero4 = {0.f, 0.f, 0.f, 0.f};

    for (int t = 1; t <= MAX_ITER_N; ++t) {
        f32x4 acc[4];
#pragma unroll
        for (int nt = 0; nt < 4; ++nt) acc[nt] = zero4;
#pragma unroll
        for (int ks = 0; ks < 8; ++ks)
#pragma unroll
            for (int nt = 0; nt < 4; ++nt)
                acc[nt] = __builtin_amdgcn_mfma_f32_16x16x32_bf16(zfr[ks], wzfr[nt][ks], acc[nt], 0, 0, 0);
        float vals[4][4];
#pragma unroll
        for (int nt = 0; nt < 4; ++nt)
#pragma unroll
            for (int i = 0; i < 4; ++i) {
                float v = acc[nt][i] + bpv[nt];
                if (colg[nt] >= FREE_NUM_N) v = fmaxf(v, 0.0f);
                vals[nt][i] = v;
            }
        if (t == MAX_ITER_N) {
#pragma unroll
            for (int nt = 0; nt < 4; ++nt)
#pragma unroll
                for (int i = 0; i < 4; ++i)
                    zout_g[(r0 + q * 4 + i) * OUT_DIM + colg[nt]] = vals[nt][i];
        }
        __syncthreads();   // S1: all waves done reading zS (z_{t-1})
#pragma unroll
        for (int nt = 0; nt < 4; ++nt)
#pragma unroll
            for (int i = 0; i < 4; ++i)
                zS[q * 4 + i][colg[nt]] = f2bf(vals[nt][i]);
        __syncthreads();   // S2: zS = z_t complete
#pragma unroll
        for (int ks = 0; ks < 8; ++ks)
            zfr[ks] = __builtin_bit_cast(bf16x8, *(const uint4*)&zS[ln][ks * 32 + q * 8]);

        f32x4 acc2[2];
        acc2[0] = zero4; acc2[1] = zero4;
#pragma unroll
        for (int ks = 0; ks < 8; ++ks)
#pragma unroll
            for (int mt = 0; mt < 2; ++mt)
                acc2[mt] = __builtin_amdgcn_mfma_f32_16x16x32_bf16(zfr[ks], afr[mt][ks], acc2[mt], 0, 0, 0);
        float lmax = 0.0f;
#pragma unroll
        for (int mt = 0; mt < 2; ++mt)
#pragma unroll
            for (int i = 0; i < 4; ++i)
                lmax = fmaxf(lmax, fabsf(acc2[mt][i] - bvv[mt]));
#pragma unroll
        for (int off = 32; off > 0; off >>= 1)
            lmax = fmaxf(lmax, __shfl_xor(lmax, off));
        if (lane == 0) red[wave] = lmax;
        __syncthreads();   // S3
        if (tid == 0) {
            float bm = fmaxf(fmaxf(red[0], red[1]), fmaxf(red[2], red[3]));
            atomicMax(res + (t - 1), __float_as_uint(bm));
        }
    }
}

__global__ void decide_k(const unsigned int* __restrict__ res, int* __restrict__ ctrl,
                         float* __restrict__ out) {
    int T = MAX_ITER_N;
    for (int t = 0; t < MAX_ITER_N; ++t) {
        float r = __uint_as_float(res[t]);
        if (!(r > F_TOL_F)) { T = t + 1; break; }
    }
    ctrl[0] = T;
    out[2 * BSZ * OUT_DIM] = (float)(T + 1);
}

// Cold path: early stop at T<20 -> recompute T iterations in fp32 into out.
__global__ __launch_bounds__(256) void fallback_k(
    const float* __restrict__ z0, const float* __restrict__ Wz,
    const float* __restrict__ bp, const int* __restrict__ ctrl,
    float* __restrict__ out)
{
    const int T = ctrl[0];
    if (T >= MAX_ITER_N) return;
    __shared__ float zS[16][257];
    const int r0 = blockIdx.x * 16;
    const int tid = threadIdx.x;
    const int row = tid >> 4;
    const int c0 = (tid & 15) * 16;
    for (int i = 0; i < 16; ++i) zS[row][c0 + i] = z0[(r0 + row) * OUT_DIM + c0 + i];
    __syncthreads();
    const int j = tid;
    const float bj = bp[j];
    for (int t = 0; t < T; ++t) {
        float acc[16] = {};
        for (int k = 0; k < OUT_DIM; ++k) {
            float w = Wz[j * OUT_DIM + k];
#pragma unroll
            for (int r = 0; r < 16; ++r) acc[r] += zS[r][k] * w;
        }
        __syncthreads();
#pragma unroll
        for (int r = 0; r < 16; ++r) {
            float v = acc[r] + bj;
            if (j >= FREE_NUM_N) v = fmaxf(v, 0.0f);
            zS[r][j] = v;
        }
        __syncthreads();
    }
    for (int i = 0; i < 16; ++i) out[(r0 + row) * OUT_DIM + c0 + i] = zS[row][c0 + i];
}

extern "C" void kernel_launch(void* const* d_in, const int* in_sizes, int n_in,
                              void* d_out, int out_size, void* d_ws, size_t ws_size,
                              hipStream_t stream) {
    const float* b_primal = (const float*)d_in[0];
    const float* W0     = (const float*)d_in[1];
    const float* b0     = (const float*)d_in[2];
    const float* W1     = (const float*)d_in[3];
    const float* b1     = (const float*)d_in[4];
    const float* W2     = (const float*)d_in[5];
    const float* b2     = (const float*)d_in[6];
    const float* Amat   = (const float*)d_in[7];
    const float* b_vec  = (const float*)d_in[8];
    const float* WzProj = (const float*)d_in[9];
    const float* WbProj = (const float*)d_in[10];
    float* out = (float*)d_out;
    float* ws  = (float*)d_ws;

    float* bp = ws + WS_BP;
    unsigned int* res = (unsigned int*)(ws + WS_RES);
    int* ctrl = (int*)(ws + WS_CTRL);
    unsigned short* h1c = (unsigned short*)(ws + WS_H1);
    unsigned short* h2c = (unsigned short*)(ws + WS_H2);
    unsigned short* APc = (unsigned short*)(ws + WS_APC);
    unsigned short* W0c = (unsigned short*)(ws + WS_W0C);
    unsigned short* W1c = (unsigned short*)(ws + WS_W1C);
    unsigned short* W2c = (unsigned short*)(ws + WS_W2C);
    unsigned short* WzG = (unsigned short*)(ws + WS_WZG);
    unsigned short* AG  = (unsigned short*)(ws + WS_AG);

    float* outz = out + BSZ * OUT_DIM;  // MLP output chunk (z_0)

    hipLaunchKernelGGL(prep_k, dim3(2401), dim3(256), 0, stream,
                       b_primal, W0, W1, W2, WzProj, Amat, b_vec, WbProj,
                       APc, W0c, W1c, W2c, WzG, AG, bp, res);

    hipLaunchKernelGGL((mfma_gemm<IN_DIM, true, false>), dim3(HID / 64, BSZ / 64), dim3(256),
                       0, stream, APc, W0c, b0, (void*)h1c, HID);
    hipLaunchKernelGGL((mfma_gemm<HID, true, false>), dim3(HID / 64, BSZ / 64), dim3(256),
                       0, stream, h1c, W1c, b1, (void*)h2c, HID);
    hipLaunchKernelGGL((mfma_gemm<HID, false, true>), dim3(OUT_DIM / 64, BSZ / 64), dim3(256),
                       0, stream, h2c, W2c, b2, (void*)outz, OUT_DIM);

    hipLaunchKernelGGL(loop_fused_k, dim3(BSZ / 16), dim3(256), 0, stream,
                       outz, WzG, AG, bp, b_vec, out, res);
    hipLaunchKernelGGL(decide_k, dim3(1), dim3(1), 0, stream, res, ctrl, out);
    hipLaunchKernelGGL(fallback_k, dim3(BSZ / 16), dim3(256), 0, stream,
                       outz, WzProj, bp, ctrl, out);
}